// Round 14
// baseline (631.275 us; speedup 1.0000x reference)
//
#include <hip/hip_runtime.h>

constexpr int BB = 512, T = 128, N = 32, M = 16, P = 16;
constexpr int NP = N * P;   // 512
constexpr int NN = N * N;   // 1024
constexpr int NM = N * M;   // 512

typedef float f4 __attribute__((ext_vector_type(4)));   // nt-store compatible

// LDS-only barrier: orders LDS producer->consumer without draining global stores.
__device__ __forceinline__ void bar_lds() {
    asm volatile("s_waitcnt lgkmcnt(0)" ::: "memory");
    __builtin_amdgcn_s_barrier();
    asm volatile("" ::: "memory");
}

// float4 loads from GLOBAL only (proven); LDS is always accessed scalar.
__device__ __forceinline__ void load_row32(const float* __restrict__ src, float* dst) {
    const float4* s4 = reinterpret_cast<const float4*>(src);
    #pragma unroll
    for (int c = 0; c < 8; ++c) {
        float4 v = s4[c];
        dst[4*c+0] = v.x; dst[4*c+1] = v.y; dst[4*c+2] = v.z; dst[4*c+3] = v.w;
    }
}
__device__ __forceinline__ void load_row16(const float* __restrict__ src, float* dst) {
    const float4* s4 = reinterpret_cast<const float4*>(src);
    #pragma unroll
    for (int c = 0; c < 4; ++c) {
        float4 v = s4[c];
        dst[4*c+0] = v.x; dst[4*c+1] = v.y; dst[4*c+2] = v.z; dst[4*c+3] = v.w;
    }
}

// ---------------- K1: serial forward Riccati (R13 verbatim, TOL=1e-4) ----------
__global__ __launch_bounds__(256) void k_fwd(
    const float* __restrict__ A, const float* __restrict__ C,
    const float* __restrict__ Q, const float* __restrict__ R,
    const float* __restrict__ Sigma0,
    float* __restrict__ K_all, float* __restrict__ Sp_all, float* __restrict__ Sf_all,
    int* __restrict__ tconv_out)
{
    __shared__ float A_l[N][N + 1], C_l[P][N + 1], Q_l[N][N + 1], R_l[P][P + 1];
    __shared__ float Sig[N][N + 1], Tmp[N][N + 1], Sp[N][N + 1], CP[P][N + 1];
    __shared__ float Aug[P][49];
    __shared__ float red[4];
    const int tid = threadIdx.x;
    const int i0 = tid >> 5, j = tid & 31;
    const int pD = tid >> 4, q = tid & 15;
    const float TOL = 1e-4f;

    for (int idx = tid; idx < NN; idx += 256) {
        A_l[idx >> 5][idx & 31] = A[idx];
        Q_l[idx >> 5][idx & 31] = Q[idx];
        Sig[idx >> 5][idx & 31] = Sigma0[idx];
    }
    for (int idx = tid; idx < P * N; idx += 256) C_l[idx >> 5][idx & 31] = C[idx];
    for (int idx = tid; idx < P * P; idx += 256) R_l[idx >> 4][idx & 15] = R[idx];
    bar_lds();

    float Arow[4][32], Cq[32], Qjv[4];
    #pragma unroll
    for (int e = 0; e < 4; ++e) {
        #pragma unroll
        for (int k = 0; k < 32; ++k) Arow[e][k] = A_l[i0 + 8*e][k];
        Qjv[e] = Q_l[j][i0 + 8*e];
    }
    #pragma unroll
    for (int k = 0; k < 32; ++k) Cq[k] = C_l[q][k];
    const float Rv = R_l[pD][q];

    float prevSig[4];
    #pragma unroll
    for (int e = 0; e < 4; ++e) prevSig[e] = Sig[i0 + 8*e][j];

    int t_conv = T;

    for (int t = 0; t < T; ++t) {
        {
            float sc[32];
            #pragma unroll
            for (int k = 0; k < 32; ++k) sc[k] = Sig[k][j];
            #pragma unroll
            for (int e = 0; e < 4; ++e) {
                float s = 0.f;
                #pragma unroll
                for (int k = 0; k < 32; ++k) s += Arow[e][k] * sc[k];
                Tmp[i0 + 8*e][j] = s;
            }
        }
        bar_lds();
        {
            float tr[32];
            #pragma unroll
            for (int k = 0; k < 32; ++k) tr[k] = Tmp[j][k];
            #pragma unroll
            for (int e = 0; e < 4; ++e) {
                const int c = i0 + 8*e;
                float s = Qjv[e];
                #pragma unroll
                for (int k = 0; k < 32; ++k) s += tr[k] * Arow[e][k];
                Sp[j][c] = s;
                Sp_all[t * NN + tid + 256*e] = s;
            }
        }
        bar_lds();
        {
            float spc[32];
            #pragma unroll
            for (int k = 0; k < 32; ++k) spc[k] = Sp[k][j];
            #pragma unroll
            for (int e = 0; e < 2; ++e) {
                const int p = i0 + 8*e;
                float s = 0.f;
                #pragma unroll
                for (int k = 0; k < 32; ++k) s += C_l[p][k] * spc[k];
                CP[p][j] = s;
            }
        }
        bar_lds();
        {
            float cpr[32];
            #pragma unroll
            for (int k = 0; k < 32; ++k) cpr[k] = CP[pD][k];
            float s = Rv;
            #pragma unroll
            for (int k = 0; k < 32; ++k) s += cpr[k] * Cq[k];
            Aug[pD][q] = s;
        }
        #pragma unroll
        for (int e = 0; e < 2; ++e) {
            const int p = i0 + 8*e;
            Aug[p][16 + j] = CP[p][j];
        }
        bar_lds();
        if (tid < 64) {
            const int r = tid >> 2, qd = tid & 3;
            float a[12];
            #pragma unroll
            for (int c = 0; c < 12; ++c) a[c] = Aug[r][qd * 12 + c];
            #pragma unroll
            for (int p = 0; p < P; ++p) {
                const int pq = p / 12;
                const int lp = p - 12 * pq;
                const float pivv = __shfl(a[lp], (p << 2) + pq);
                const float f    = __shfl(a[lp], (tid & ~3) + pq);
                const float pinv = 1.0f / pivv;
                const float fp = f * pinv;
                float pr[12];
                #pragma unroll
                for (int c = 0; c < 12; ++c) pr[c] = __shfl(a[c], (p << 2) + qd);
                #pragma unroll
                for (int c = 0; c < 12; ++c)
                    a[c] = (r == p) ? pr[c] * pinv : a[c] - fp * pr[c];
            }
            if (qd) {
                #pragma unroll
                for (int c = 0; c < 12; ++c) Aug[r][qd * 12 + c] = a[c];
            }
        }
        bar_lds();
        #pragma unroll
        for (int e = 0; e < 2; ++e) {
            const int idx = tid + 256*e;
            K_all[t * NP + idx] = Aug[idx & 15][16 + (idx >> 4)];
        }
        float wmax = 0.f;
        {
            float cpj[16];
            #pragma unroll
            for (int p = 0; p < 16; ++p) cpj[p] = CP[p][j];
            #pragma unroll
            for (int e = 0; e < 4; ++e) {
                const int i = i0 + 8*e;
                float s = Sp[i][j];
                #pragma unroll
                for (int p = 0; p < 16; ++p) s -= Aug[p][16 + i] * cpj[p];
                Sig[i][j] = s;
                Sf_all[t * NN + tid + 256*e] = s;
                wmax = fmaxf(wmax, fabsf(s - prevSig[e]));
                prevSig[e] = s;
            }
        }
        #pragma unroll
        for (int m = 1; m < 64; m <<= 1)
            wmax = fmaxf(wmax, __shfl_xor(wmax, m));
        if ((tid & 63) == 0) red[tid >> 6] = wmax;
        bar_lds();
        const float g = fmaxf(fmaxf(red[0], red[1]), fmaxf(red[2], red[3]));
        if (g <= TOL && t < T - 1) { t_conv = t; break; }
    }

    if (t_conv < T - 1) {
        float kv[2], spv[4], sfv[4];
        #pragma unroll
        for (int e = 0; e < 2; ++e) {
            const int idx = tid + 256*e;
            kv[e] = Aug[idx & 15][16 + (idx >> 4)];
        }
        #pragma unroll
        for (int e = 0; e < 4; ++e) {
            spv[e] = Sp[i0 + 8*e][j];
            sfv[e] = Sig[i0 + 8*e][j];
        }
        for (int s = t_conv + 1; s < T; ++s) {
            #pragma unroll
            for (int e = 0; e < 2; ++e) K_all[s * NP + tid + 256*e] = kv[e];
            #pragma unroll
            for (int e = 0; e < 4; ++e) {
                Sp_all[s * NN + tid + 256*e] = spv[e];
                Sf_all[s * NN + tid + 256*e] = sfv[e];
            }
        }
    }
    if (tid == 0) *tconv_out = t_conv;
}

// ---------------- K2: fused J,H (t<T-1) + G,D,E,F per t ------------------------
// J/H section verbatim from the passing k_jh; then W reused for K*C.
// G_t=(I-K_tC)A, D_t=(I-K_tC)B (all t); E_t=I-J_tA, F_t=J_tB (t<T-1, Jl in LDS).
__global__ __launch_bounds__(256) void k_jhm(
    const float* __restrict__ A, const float* __restrict__ C, const float* __restrict__ Bm,
    const float* __restrict__ Sp_all, const float* __restrict__ Sf_all,
    const float* __restrict__ K_all,
    float* __restrict__ J_all, float* __restrict__ H_all,
    float* __restrict__ G_all, float* __restrict__ D_all,
    float* __restrict__ E_all, float* __restrict__ F_all)
{
    const int t = blockIdx.x;  // 0..T-1
    __shared__ float A_l[N][N + 1], Sf[N][N + 1], Sp1[N][N + 1];
    __shared__ float Aug[N][65], W[N][N + 1], Jl[N][N + 1];
    __shared__ float C_l[P][N + 1], B_l[N][M + 1], Kl[N][P + 1];
    const int tid = threadIdx.x;
    const bool hasJ = (t < T - 1);   // block-uniform

    for (int idx = tid; idx < NN; idx += 256) A_l[idx >> 5][idx & 31] = A[idx];
    for (int idx = tid; idx < P * N; idx += 256) C_l[idx >> 5][idx & 31] = C[idx];
    for (int idx = tid; idx < NM; idx += 256) B_l[idx >> 4][idx & 15] = Bm[idx];
    for (int idx = tid; idx < NP; idx += 256) Kl[idx >> 4][idx & 15] = K_all[t * NP + idx];
    if (hasJ) {
        for (int idx = tid; idx < NN; idx += 256) {
            Sf[idx >> 5][idx & 31]  = Sf_all[t * NN + idx];
            Sp1[idx >> 5][idx & 31] = Sp_all[(t + 1) * NN + idx];
        }
    }
    __syncthreads();

    if (hasJ) {
        // Aug = [Sp1 | A*Sf]
        #pragma unroll
        for (int e = 0; e < 4; ++e) {
            int idx = tid + e * 256; int i = idx >> 5, j = idx & 31;
            float s = 0.f;
            #pragma unroll
            for (int k = 0; k < N; ++k) s += A_l[i][k] * Sf[k][j];
            Aug[i][32 + j] = s;
            Aug[i][j] = Sp1[i][j];
        }
        __syncthreads();
        {
            int r = tid >> 3, c0 = (tid & 7) * 8;
            for (int p = 0; p < N; ++p) {
                float pinv = 1.0f / Aug[p][p];
                float f = Aug[r][p];
                float prow[8], mine[8];
                #pragma unroll
                for (int c = 0; c < 8; ++c) { prow[c] = Aug[p][c0 + c]; mine[c] = Aug[r][c0 + c]; }
                __syncthreads();
                float fp = f * pinv;
                #pragma unroll
                for (int c = 0; c < 8; ++c)
                    Aug[r][c0 + c] = (r == p) ? prow[c] * pinv : mine[c] - fp * prow[c];
                __syncthreads();
            }
        }
        #pragma unroll
        for (int e = 0; e < 4; ++e) {
            int idx = tid + e * 256; int i = idx >> 5, j = idx & 31;
            float v = Aug[j][32 + i];
            Jl[i][j] = v;
            J_all[t * NN + idx] = v;
        }
        __syncthreads();
        #pragma unroll
        for (int e = 0; e < 4; ++e) {
            int idx = tid + e * 256; int i = idx >> 5, j = idx & 31;
            float s = 0.f;
            #pragma unroll
            for (int k = 0; k < N; ++k) s += Jl[i][k] * Sp1[k][j];
            W[i][j] = s;
        }
        __syncthreads();
        #pragma unroll
        for (int e = 0; e < 4; ++e) {
            int idx = tid + e * 256; int i = idx >> 5, j = idx & 31;
            float s = Sf[i][j];
            #pragma unroll
            for (int k = 0; k < N; ++k) s -= W[i][k] * Jl[j][k];
            H_all[t * NN + idx] = s;
        }
    }
    __syncthreads();   // H reads of W done before overwrite
    // W = K_t * C
    #pragma unroll
    for (int e = 0; e < 4; ++e) {
        int idx = tid + e * 256; int i = idx >> 5, j = idx & 31;
        float s = 0.f;
        #pragma unroll
        for (int p = 0; p < P; ++p) s += Kl[i][p] * C_l[p][j];
        W[i][j] = s;
    }
    __syncthreads();
    // G = A - W*A ; D = B - W*B
    #pragma unroll
    for (int e = 0; e < 4; ++e) {
        int idx = tid + e * 256; int i = idx >> 5, j = idx & 31;
        float s = A_l[i][j];
        #pragma unroll
        for (int k = 0; k < N; ++k) s -= W[i][k] * A_l[k][j];
        G_all[t * NN + idx] = s;
    }
    #pragma unroll
    for (int e = 0; e < 2; ++e) {
        int idx = tid + e * 256; int i = idx >> 4, m = idx & 15;
        float s = B_l[i][m];
        #pragma unroll
        for (int k = 0; k < N; ++k) s -= W[i][k] * B_l[k][m];
        D_all[t * NM + idx] = s;
    }
    if (hasJ) {
        // E = I - J*A ; F = J*B   (Jl still valid)
        #pragma unroll
        for (int e = 0; e < 4; ++e) {
            int idx = tid + e * 256; int i = idx >> 5, j = idx & 31;
            float s = (i == j) ? 1.f : 0.f;
            #pragma unroll
            for (int k = 0; k < N; ++k) s -= Jl[i][k] * A_l[k][j];
            E_all[t * NN + idx] = s;
        }
        #pragma unroll
        for (int e = 0; e < 2; ++e) {
            int idx = tid + e * 256; int i = idx >> 4, m = idx & 15;
            float s = 0.f;
            #pragma unroll
            for (int k = 0; k < N; ++k) s += Jl[i][k] * B_l[k][m];
            F_all[t * NM + idx] = s;
        }
    }
}

// ---------------- K3: smoother covariance scan + plateau skip (TOL=1e-3) -------
// Ss freeze error ~ TOL*r/(1-r) ~ 3e-3 (direct, no K-amplification) — safe.
__global__ __launch_bounds__(256) void k_sscan(
    const float* __restrict__ Sf_all,
    const float* __restrict__ J_all, const float* __restrict__ H_all,
    float* __restrict__ Ss_all, const int* __restrict__ tconv_ptr)
{
    __shared__ float Ss[N][N + 1], W[N][N + 1], Hl[N][N + 1];
    __shared__ float red[4];
    const int tid = threadIdx.x;
    const int i0 = tid >> 5, j = tid & 31;
    const int t_conv = *tconv_ptr;
    const float TOL = 1e-3f;

    for (int idx = tid; idx < NN; idx += 256) {
        float v = Sf_all[(size_t)(T - 1) * NN + idx];
        Ss[idx >> 5][idx & 31] = v;
        Ss_all[(size_t)(T - 1) * NN + idx] = v;
    }
    bar_lds();
    float prevSs[4];
    #pragma unroll
    for (int e = 0; e < 4; ++e) prevSs[e] = Ss[j][i0 + 8*e];

    for (int t = T - 2; t >= 0; --t) {
        float jr[4][32];
        #pragma unroll
        for (int e = 0; e < 4; ++e)
            load_row32(J_all + (size_t)t * NN + (i0 + 8*e) * 32, jr[e]);
        #pragma unroll
        for (int e = 0; e < 4; ++e)
            Hl[i0 + 8*e][j] = H_all[(size_t)t * NN + tid + 256*e];
        {
            float sc[32];
            #pragma unroll
            for (int k = 0; k < 32; ++k) sc[k] = Ss[k][j];
            #pragma unroll
            for (int e = 0; e < 4; ++e) {
                float s = 0.f;
                #pragma unroll
                for (int k = 0; k < 32; ++k) s += jr[e][k] * sc[k];
                W[i0 + 8*e][j] = s;
            }
        }
        bar_lds();
        float localmax = 0.f;
        {
            float wr[32];
            #pragma unroll
            for (int k = 0; k < 32; ++k) wr[k] = W[j][k];
            #pragma unroll
            for (int e = 0; e < 4; ++e) {
                const int c = i0 + 8*e;
                float s = Hl[j][c];
                #pragma unroll
                for (int k = 0; k < 32; ++k) s += wr[k] * jr[e][k];
                Ss[j][c] = s;
                Ss_all[(size_t)t * NN + tid + 256*e] = s;
                localmax = fmaxf(localmax, fabsf(s - prevSs[e]));
                prevSs[e] = s;
            }
        }
        #pragma unroll
        for (int m = 1; m < 64; m <<= 1)
            localmax = fmaxf(localmax, __shfl_xor(localmax, m));
        if ((tid & 63) == 0) red[tid >> 6] = localmax;
        bar_lds();
        const float g = fmaxf(fmaxf(red[0], red[1]), fmaxf(red[2], red[3]));
        if (g <= TOL && (t - 1 >= t_conv)) {
            for (int s = t_conv; s <= t - 1; ++s) {
                #pragma unroll
                for (int e = 0; e < 4; ++e)
                    Ss_all[(size_t)s * NN + tid + 256*e] = prevSs[e];
            }
            t = t_conv;
        }
    }
}

// ---------------- K4: means; TWO batches per wave (lanes 0-31 / 32-63) ---------
// Each half-wave runs one batch's chains; two independent serial chains
// interleave in one instruction stream -> latency amortized 2x.
// shfl pulls stay within the half via index k + (lane & 32).
__global__ __launch_bounds__(64, 1) void k_mu(
    const float* __restrict__ Y, const float* __restrict__ U,
    const float* __restrict__ mu0,
    const float* __restrict__ K_all, const float* __restrict__ J_all,
    const float* __restrict__ G_all, const float* __restrict__ D_all,
    const float* __restrict__ E_all, const float* __restrict__ F_all,
    const int* __restrict__ tconv_ptr,
    float* __restrict__ out_mus)
{
    const int lane = threadIdx.x;
    const int j = lane & 31;
    const int h = lane >> 5;                  // batch selector in block
    const int b = blockIdx.x * 2 + h;
    const int sb = lane & 32;                 // shfl half-base
    __shared__ float mfh[2][T][N];
    __shared__ float cfh[2][T][N];
    const int t_conv = *tconv_ptr;
    const float* Yb = Y + (size_t)b * T * P;
    const float* Ub = U + (size_t)b * T * M;

    // ---- forward pre-pass: c[t][j] = D_t[j,:]u_t + K_t[j,:]y_t ----
    for (int t = 0; t < T; ++t) {
        float dr[16], kr[16], uu[16], yy[16];
        load_row16(D_all + t * NM + j * 16, dr);
        load_row16(K_all + t * NP + j * 16, kr);
        load_row16(Ub + t * M, uu);
        load_row16(Yb + t * P, yy);
        float s0 = 0.f, s1 = 0.f, s2 = 0.f, s3 = 0.f;
        #pragma unroll
        for (int m = 0; m < 16; m += 4) {
            s0 += dr[m+0]*uu[m+0]; s1 += dr[m+1]*uu[m+1];
            s2 += dr[m+2]*uu[m+2]; s3 += dr[m+3]*uu[m+3];
            s0 += kr[m+0]*yy[m+0]; s1 += kr[m+1]*yy[m+1];
            s2 += kr[m+2]*yy[m+2]; s3 += kr[m+3]*yy[m+3];
        }
        cfh[h][t][j] = (s0 + s1) + (s2 + s3);
    }
    __syncthreads();

    // ---- forward chain: mu = G_t mu + c_t ----
    float mu = mu0[j];
    float gr[32];
    load_row32(G_all + j * 32, gr);
    const int tv = (t_conv < T - 1) ? t_conv : (T - 1);
    float cn = cfh[h][0][j];
    int t = 0;
    for (; t < tv; ++t) {           // varying phase: per-step prefetch
        float grn[32];
        load_row32(G_all + (size_t)(t + 1) * NN + j * 32, grn);
        const float cnn = cfh[h][t + 1][j];
        float s0 = 0.f, s1 = 0.f, s2 = 0.f, s3 = 0.f;
        #pragma unroll
        for (int k = 0; k < 32; k += 4) {
            s0 += gr[k+0] * __shfl(mu, k+0+sb);
            s1 += gr[k+1] * __shfl(mu, k+1+sb);
            s2 += gr[k+2] * __shfl(mu, k+2+sb);
            s3 += gr[k+3] * __shfl(mu, k+3+sb);
        }
        mu = ((s0 + s1) + (s2 + s3)) + cn;
        mfh[h][t][j] = mu;
        #pragma unroll
        for (int c = 0; c < 32; ++c) gr[c] = grn[c];
        cn = cnn;
    }
    for (; t < T; ++t) {            // plateau: gr constant, zero loads
        const float cnn = (t + 1 < T) ? cfh[h][t + 1][j] : 0.f;
        float s0 = 0.f, s1 = 0.f, s2 = 0.f, s3 = 0.f;
        #pragma unroll
        for (int k = 0; k < 32; k += 4) {
            s0 += gr[k+0] * __shfl(mu, k+0+sb);
            s1 += gr[k+1] * __shfl(mu, k+1+sb);
            s2 += gr[k+2] * __shfl(mu, k+2+sb);
            s3 += gr[k+3] * __shfl(mu, k+3+sb);
        }
        mu = ((s0 + s1) + (s2 + s3)) + cn;
        mfh[h][t][j] = mu;
        cn = cnn;
    }
    out_mus[((size_t)b * T + (T - 1)) * N + j] = mu;
    __syncthreads();

    // ---- backward pre-pass: cb[t][j] = E_t[j,:]mfh[t] - F_t[j,:]u(t+1) ----
    for (int tt = 0; tt < T - 1; ++tt) {
        float er[32], fr[16], uu[16];
        load_row32(E_all + (size_t)tt * NN + j * 32, er);
        load_row16(F_all + tt * NM + j * 16, fr);
        load_row16(Ub + (tt + 1) * M, uu);
        float s0 = 0.f, s1 = 0.f, s2 = 0.f, s3 = 0.f;
        #pragma unroll
        for (int k = 0; k < 32; k += 4) {
            s0 += er[k+0] * mfh[h][tt][k+0];
            s1 += er[k+1] * mfh[h][tt][k+1];
            s2 += er[k+2] * mfh[h][tt][k+2];
            s3 += er[k+3] * mfh[h][tt][k+3];
        }
        #pragma unroll
        for (int m = 0; m < 16; m += 4) {
            s0 -= fr[m+0]*uu[m+0]; s1 -= fr[m+1]*uu[m+1];
            s2 -= fr[m+2]*uu[m+2]; s3 -= fr[m+3]*uu[m+3];
        }
        cfh[h][tt][j] = (s0 + s1) + (s2 + s3);
    }
    __syncthreads();

    // ---- backward chain: ms = J_t ms + cb_t ----
    float ms = mu;
    const int tp = (t_conv < T - 2) ? t_conv : (T - 2);
    float jr[32];
    load_row32(J_all + (size_t)tp * NN + j * 32, jr);   // J constant on [tp, T-2]
    float cb = cfh[h][T - 2][j];
    for (t = T - 2; t >= tp; --t) {   // plateau: jr constant, zero loads
        const float cbn = (t - 1 >= 0) ? cfh[h][t - 1][j] : 0.f;
        float s0 = 0.f, s1 = 0.f, s2 = 0.f, s3 = 0.f;
        #pragma unroll
        for (int k = 0; k < 32; k += 4) {
            s0 += jr[k+0] * __shfl(ms, k+0+sb);
            s1 += jr[k+1] * __shfl(ms, k+1+sb);
            s2 += jr[k+2] * __shfl(ms, k+2+sb);
            s3 += jr[k+3] * __shfl(ms, k+3+sb);
        }
        ms = ((s0 + s1) + (s2 + s3)) + cb;
        out_mus[((size_t)b * T + t) * N + j] = ms;
        cb = cbn;
    }
    if (t >= 0) {
        load_row32(J_all + (size_t)t * NN + j * 32, jr);   // J_{tp-1}
        for (; t >= 0; --t) {          // varying phase: per-step prefetch
            float jrn[32];
            #pragma unroll
            for (int c = 0; c < 32; ++c) jrn[c] = 0.f;
            if (t > 0) load_row32(J_all + (size_t)(t - 1) * NN + j * 32, jrn);
            const float cbn = (t - 1 >= 0) ? cfh[h][t - 1][j] : 0.f;
            float s0 = 0.f, s1 = 0.f, s2 = 0.f, s3 = 0.f;
            #pragma unroll
            for (int k = 0; k < 32; k += 4) {
                s0 += jr[k+0] * __shfl(ms, k+0+sb);
                s1 += jr[k+1] * __shfl(ms, k+1+sb);
                s2 += jr[k+2] * __shfl(ms, k+2+sb);
                s3 += jr[k+3] * __shfl(ms, k+3+sb);
            }
            ms = ((s0 + s1) + (s2 + s3)) + cb;
            out_mus[((size_t)b * T + t) * N + j] = ms;
            cb = cbn;
            #pragma unroll
            for (int c = 0; c < 32; ++c) jr[c] = jrn[c];
        }
    }
}

// ---------------- K5: broadcast Sig_s tiles (nt stream write, verbatim) --------
__global__ __launch_bounds__(256) void k_bcast(
    const float* __restrict__ Ss_all, f4* __restrict__ out4)
{
    const f4* src = (const f4*)Ss_all;
    const long long total = (long long)BB * T * (NN / 4);
    const long long stride = (long long)gridDim.x * blockDim.x;
    for (long long g = blockIdx.x * (long long)blockDim.x + threadIdx.x; g < total; g += stride) {
        int e4 = (int)(g & 255);
        long long bt = g >> 8;
        int t = (int)(bt & (T - 1));
        __builtin_nontemporal_store(src[t * 256 + e4], &out4[g]);
    }
}

extern "C" void kernel_launch(void* const* d_in, const int* in_sizes, int n_in,
                              void* d_out, int out_size, void* d_ws, size_t ws_size,
                              hipStream_t stream)
{
    (void)in_sizes; (void)n_in; (void)out_size; (void)ws_size;
    const float* Y      = (const float*)d_in[0];
    const float* U      = (const float*)d_in[1];
    const float* A      = (const float*)d_in[2];
    const float* Bm     = (const float*)d_in[3];
    const float* C      = (const float*)d_in[4];
    const float* mu0    = (const float*)d_in[5];
    const float* Sigma0 = (const float*)d_in[6];
    const float* Q      = (const float*)d_in[7];
    const float* R      = (const float*)d_in[8];

    float* ws     = (float*)d_ws;
    float* K_all  = ws;
    float* Sp_all = K_all + T * NP;
    float* Sf_all = Sp_all + T * NN;
    float* J_all  = Sf_all + T * NN;
    float* H_all  = J_all + T * NN;
    float* Ss_all = H_all + T * NN;
    float* G_all  = Ss_all + T * NN;
    float* D_all  = G_all + T * NN;
    float* E_all  = D_all + T * NM;
    float* F_all  = E_all + T * NN;
    int*   tconv  = (int*)(F_all + T * NM);

    float* out_mus  = (float*)d_out;
    float* out_sigs = out_mus + (size_t)BB * T * N;

    hipLaunchKernelGGL(k_fwd,   dim3(1),      dim3(256), 0, stream, A, C, Q, R, Sigma0, K_all, Sp_all, Sf_all, tconv);
    hipLaunchKernelGGL(k_jhm,   dim3(T),      dim3(256), 0, stream, A, C, Bm, Sp_all, Sf_all, K_all, J_all, H_all, G_all, D_all, E_all, F_all);
    hipLaunchKernelGGL(k_sscan, dim3(1),      dim3(256), 0, stream, Sf_all, J_all, H_all, Ss_all, tconv);
    hipLaunchKernelGGL(k_mu,    dim3(BB / 2), dim3(64),  0, stream, Y, U, mu0, K_all, J_all, G_all, D_all, E_all, F_all, tconv, out_mus);
    hipLaunchKernelGGL(k_bcast, dim3(4096),   dim3(256), 0, stream, Ss_all, (f4*)out_sigs);
}

// Round 15
// 568.316 us; speedup vs baseline: 1.1108x; 1.1108x over previous
//
#include <hip/hip_runtime.h>

constexpr int BB = 512, T = 128, N = 32, M = 16, P = 16;
constexpr int NP = N * P;   // 512
constexpr int NN = N * N;   // 1024
constexpr int NM = N * M;   // 512

typedef float f4 __attribute__((ext_vector_type(4)));   // nt-store compatible

// LDS-only barrier: orders LDS producer->consumer without draining global stores.
__device__ __forceinline__ void bar_lds() {
    asm volatile("s_waitcnt lgkmcnt(0)" ::: "memory");
    __builtin_amdgcn_s_barrier();
    asm volatile("" ::: "memory");
}

// float4 loads from GLOBAL only (proven); LDS is always accessed scalar.
__device__ __forceinline__ void load_row32(const float* __restrict__ src, float* dst) {
    const float4* s4 = reinterpret_cast<const float4*>(src);
    #pragma unroll
    for (int c = 0; c < 8; ++c) {
        float4 v = s4[c];
        dst[4*c+0] = v.x; dst[4*c+1] = v.y; dst[4*c+2] = v.z; dst[4*c+3] = v.w;
    }
}
__device__ __forceinline__ void load_row16(const float* __restrict__ src, float* dst) {
    const float4* s4 = reinterpret_cast<const float4*>(src);
    #pragma unroll
    for (int c = 0; c < 4; ++c) {
        float4 v = s4[c];
        dst[4*c+0] = v.x; dst[4*c+1] = v.y; dst[4*c+2] = v.z; dst[4*c+3] = v.w;
    }
}

// ---------------- K1: serial forward Riccati (R13 verbatim, TOL=1e-4) ----------
__global__ __launch_bounds__(256) void k_fwd(
    const float* __restrict__ A, const float* __restrict__ C,
    const float* __restrict__ Q, const float* __restrict__ R,
    const float* __restrict__ Sigma0,
    float* __restrict__ K_all, float* __restrict__ Sp_all, float* __restrict__ Sf_all,
    int* __restrict__ tconv_out)
{
    __shared__ float A_l[N][N + 1], C_l[P][N + 1], Q_l[N][N + 1], R_l[P][P + 1];
    __shared__ float Sig[N][N + 1], Tmp[N][N + 1], Sp[N][N + 1], CP[P][N + 1];
    __shared__ float Aug[P][49];
    __shared__ float red[4];
    const int tid = threadIdx.x;
    const int i0 = tid >> 5, j = tid & 31;
    const int pD = tid >> 4, q = tid & 15;
    const float TOL = 1e-4f;

    for (int idx = tid; idx < NN; idx += 256) {
        A_l[idx >> 5][idx & 31] = A[idx];
        Q_l[idx >> 5][idx & 31] = Q[idx];
        Sig[idx >> 5][idx & 31] = Sigma0[idx];
    }
    for (int idx = tid; idx < P * N; idx += 256) C_l[idx >> 5][idx & 31] = C[idx];
    for (int idx = tid; idx < P * P; idx += 256) R_l[idx >> 4][idx & 15] = R[idx];
    bar_lds();

    float Arow[4][32], Cq[32], Qjv[4];
    #pragma unroll
    for (int e = 0; e < 4; ++e) {
        #pragma unroll
        for (int k = 0; k < 32; ++k) Arow[e][k] = A_l[i0 + 8*e][k];
        Qjv[e] = Q_l[j][i0 + 8*e];
    }
    #pragma unroll
    for (int k = 0; k < 32; ++k) Cq[k] = C_l[q][k];
    const float Rv = R_l[pD][q];

    float prevSig[4];
    #pragma unroll
    for (int e = 0; e < 4; ++e) prevSig[e] = Sig[i0 + 8*e][j];

    int t_conv = T;

    for (int t = 0; t < T; ++t) {
        {
            float sc[32];
            #pragma unroll
            for (int k = 0; k < 32; ++k) sc[k] = Sig[k][j];
            #pragma unroll
            for (int e = 0; e < 4; ++e) {
                float s = 0.f;
                #pragma unroll
                for (int k = 0; k < 32; ++k) s += Arow[e][k] * sc[k];
                Tmp[i0 + 8*e][j] = s;
            }
        }
        bar_lds();
        {
            float tr[32];
            #pragma unroll
            for (int k = 0; k < 32; ++k) tr[k] = Tmp[j][k];
            #pragma unroll
            for (int e = 0; e < 4; ++e) {
                const int c = i0 + 8*e;
                float s = Qjv[e];
                #pragma unroll
                for (int k = 0; k < 32; ++k) s += tr[k] * Arow[e][k];
                Sp[j][c] = s;
                Sp_all[t * NN + tid + 256*e] = s;
            }
        }
        bar_lds();
        {
            float spc[32];
            #pragma unroll
            for (int k = 0; k < 32; ++k) spc[k] = Sp[k][j];
            #pragma unroll
            for (int e = 0; e < 2; ++e) {
                const int p = i0 + 8*e;
                float s = 0.f;
                #pragma unroll
                for (int k = 0; k < 32; ++k) s += C_l[p][k] * spc[k];
                CP[p][j] = s;
            }
        }
        bar_lds();
        {
            float cpr[32];
            #pragma unroll
            for (int k = 0; k < 32; ++k) cpr[k] = CP[pD][k];
            float s = Rv;
            #pragma unroll
            for (int k = 0; k < 32; ++k) s += cpr[k] * Cq[k];
            Aug[pD][q] = s;
        }
        #pragma unroll
        for (int e = 0; e < 2; ++e) {
            const int p = i0 + 8*e;
            Aug[p][16 + j] = CP[p][j];
        }
        bar_lds();
        if (tid < 64) {
            const int r = tid >> 2, qd = tid & 3;
            float a[12];
            #pragma unroll
            for (int c = 0; c < 12; ++c) a[c] = Aug[r][qd * 12 + c];
            #pragma unroll
            for (int p = 0; p < P; ++p) {
                const int pq = p / 12;
                const int lp = p - 12 * pq;
                const float pivv = __shfl(a[lp], (p << 2) + pq);
                const float f    = __shfl(a[lp], (tid & ~3) + pq);
                const float pinv = 1.0f / pivv;
                const float fp = f * pinv;
                float pr[12];
                #pragma unroll
                for (int c = 0; c < 12; ++c) pr[c] = __shfl(a[c], (p << 2) + qd);
                #pragma unroll
                for (int c = 0; c < 12; ++c)
                    a[c] = (r == p) ? pr[c] * pinv : a[c] - fp * pr[c];
            }
            if (qd) {
                #pragma unroll
                for (int c = 0; c < 12; ++c) Aug[r][qd * 12 + c] = a[c];
            }
        }
        bar_lds();
        #pragma unroll
        for (int e = 0; e < 2; ++e) {
            const int idx = tid + 256*e;
            K_all[t * NP + idx] = Aug[idx & 15][16 + (idx >> 4)];
        }
        float wmax = 0.f;
        {
            float cpj[16];
            #pragma unroll
            for (int p = 0; p < 16; ++p) cpj[p] = CP[p][j];
            #pragma unroll
            for (int e = 0; e < 4; ++e) {
                const int i = i0 + 8*e;
                float s = Sp[i][j];
                #pragma unroll
                for (int p = 0; p < 16; ++p) s -= Aug[p][16 + i] * cpj[p];
                Sig[i][j] = s;
                Sf_all[t * NN + tid + 256*e] = s;
                wmax = fmaxf(wmax, fabsf(s - prevSig[e]));
                prevSig[e] = s;
            }
        }
        #pragma unroll
        for (int m = 1; m < 64; m <<= 1)
            wmax = fmaxf(wmax, __shfl_xor(wmax, m));
        if ((tid & 63) == 0) red[tid >> 6] = wmax;
        bar_lds();
        const float g = fmaxf(fmaxf(red[0], red[1]), fmaxf(red[2], red[3]));
        if (g <= TOL && t < T - 1) { t_conv = t; break; }
    }

    if (t_conv < T - 1) {
        float kv[2], spv[4], sfv[4];
        #pragma unroll
        for (int e = 0; e < 2; ++e) {
            const int idx = tid + 256*e;
            kv[e] = Aug[idx & 15][16 + (idx >> 4)];
        }
        #pragma unroll
        for (int e = 0; e < 4; ++e) {
            spv[e] = Sp[i0 + 8*e][j];
            sfv[e] = Sig[i0 + 8*e][j];
        }
        for (int s = t_conv + 1; s < T; ++s) {
            #pragma unroll
            for (int e = 0; e < 2; ++e) K_all[s * NP + tid + 256*e] = kv[e];
            #pragma unroll
            for (int e = 0; e < 4; ++e) {
                Sp_all[s * NN + tid + 256*e] = spv[e];
                Sf_all[s * NN + tid + 256*e] = sfv[e];
            }
        }
    }
    if (tid == 0) *tconv_out = t_conv;
}

// ---------------- K2: fused J,H (t<T-1) + G,D,E,F per t (R14 verbatim) ---------
__global__ __launch_bounds__(256) void k_jhm(
    const float* __restrict__ A, const float* __restrict__ C, const float* __restrict__ Bm,
    const float* __restrict__ Sp_all, const float* __restrict__ Sf_all,
    const float* __restrict__ K_all,
    float* __restrict__ J_all, float* __restrict__ H_all,
    float* __restrict__ G_all, float* __restrict__ D_all,
    float* __restrict__ E_all, float* __restrict__ F_all)
{
    const int t = blockIdx.x;  // 0..T-1
    __shared__ float A_l[N][N + 1], Sf[N][N + 1], Sp1[N][N + 1];
    __shared__ float Aug[N][65], W[N][N + 1], Jl[N][N + 1];
    __shared__ float C_l[P][N + 1], B_l[N][M + 1], Kl[N][P + 1];
    const int tid = threadIdx.x;
    const bool hasJ = (t < T - 1);   // block-uniform

    for (int idx = tid; idx < NN; idx += 256) A_l[idx >> 5][idx & 31] = A[idx];
    for (int idx = tid; idx < P * N; idx += 256) C_l[idx >> 5][idx & 31] = C[idx];
    for (int idx = tid; idx < NM; idx += 256) B_l[idx >> 4][idx & 15] = Bm[idx];
    for (int idx = tid; idx < NP; idx += 256) Kl[idx >> 4][idx & 15] = K_all[t * NP + idx];
    if (hasJ) {
        for (int idx = tid; idx < NN; idx += 256) {
            Sf[idx >> 5][idx & 31]  = Sf_all[t * NN + idx];
            Sp1[idx >> 5][idx & 31] = Sp_all[(t + 1) * NN + idx];
        }
    }
    __syncthreads();

    if (hasJ) {
        #pragma unroll
        for (int e = 0; e < 4; ++e) {
            int idx = tid + e * 256; int i = idx >> 5, j = idx & 31;
            float s = 0.f;
            #pragma unroll
            for (int k = 0; k < N; ++k) s += A_l[i][k] * Sf[k][j];
            Aug[i][32 + j] = s;
            Aug[i][j] = Sp1[i][j];
        }
        __syncthreads();
        {
            int r = tid >> 3, c0 = (tid & 7) * 8;
            for (int p = 0; p < N; ++p) {
                float pinv = 1.0f / Aug[p][p];
                float f = Aug[r][p];
                float prow[8], mine[8];
                #pragma unroll
                for (int c = 0; c < 8; ++c) { prow[c] = Aug[p][c0 + c]; mine[c] = Aug[r][c0 + c]; }
                __syncthreads();
                float fp = f * pinv;
                #pragma unroll
                for (int c = 0; c < 8; ++c)
                    Aug[r][c0 + c] = (r == p) ? prow[c] * pinv : mine[c] - fp * prow[c];
                __syncthreads();
            }
        }
        #pragma unroll
        for (int e = 0; e < 4; ++e) {
            int idx = tid + e * 256; int i = idx >> 5, j = idx & 31;
            float v = Aug[j][32 + i];
            Jl[i][j] = v;
            J_all[t * NN + idx] = v;
        }
        __syncthreads();
        #pragma unroll
        for (int e = 0; e < 4; ++e) {
            int idx = tid + e * 256; int i = idx >> 5, j = idx & 31;
            float s = 0.f;
            #pragma unroll
            for (int k = 0; k < N; ++k) s += Jl[i][k] * Sp1[k][j];
            W[i][j] = s;
        }
        __syncthreads();
        #pragma unroll
        for (int e = 0; e < 4; ++e) {
            int idx = tid + e * 256; int i = idx >> 5, j = idx & 31;
            float s = Sf[i][j];
            #pragma unroll
            for (int k = 0; k < N; ++k) s -= W[i][k] * Jl[j][k];
            H_all[t * NN + idx] = s;
        }
    }
    __syncthreads();   // H reads of W done before overwrite
    // W = K_t * C
    #pragma unroll
    for (int e = 0; e < 4; ++e) {
        int idx = tid + e * 256; int i = idx >> 5, j = idx & 31;
        float s = 0.f;
        #pragma unroll
        for (int p = 0; p < P; ++p) s += Kl[i][p] * C_l[p][j];
        W[i][j] = s;
    }
    __syncthreads();
    // G = A - W*A ; D = B - W*B
    #pragma unroll
    for (int e = 0; e < 4; ++e) {
        int idx = tid + e * 256; int i = idx >> 5, j = idx & 31;
        float s = A_l[i][j];
        #pragma unroll
        for (int k = 0; k < N; ++k) s -= W[i][k] * A_l[k][j];
        G_all[t * NN + idx] = s;
    }
    #pragma unroll
    for (int e = 0; e < 2; ++e) {
        int idx = tid + e * 256; int i = idx >> 4, m = idx & 15;
        float s = B_l[i][m];
        #pragma unroll
        for (int k = 0; k < N; ++k) s -= W[i][k] * B_l[k][m];
        D_all[t * NM + idx] = s;
    }
    if (hasJ) {
        // E = I - J*A ; F = J*B   (Jl still valid)
        #pragma unroll
        for (int e = 0; e < 4; ++e) {
            int idx = tid + e * 256; int i = idx >> 5, j = idx & 31;
            float s = (i == j) ? 1.f : 0.f;
            #pragma unroll
            for (int k = 0; k < N; ++k) s -= Jl[i][k] * A_l[k][j];
            E_all[t * NN + idx] = s;
        }
        #pragma unroll
        for (int e = 0; e < 2; ++e) {
            int idx = tid + e * 256; int i = idx >> 4, m = idx & 15;
            float s = 0.f;
            #pragma unroll
            for (int k = 0; k < N; ++k) s += Jl[i][k] * B_l[k][m];
            F_all[t * NM + idx] = s;
        }
    }
}

// ---------------- K3: smoother covariance scan + plateau skip (TOL=1e-3) -------
__global__ __launch_bounds__(256) void k_sscan(
    const float* __restrict__ Sf_all,
    const float* __restrict__ J_all, const float* __restrict__ H_all,
    float* __restrict__ Ss_all, const int* __restrict__ tconv_ptr)
{
    __shared__ float Ss[N][N + 1], W[N][N + 1], Hl[N][N + 1];
    __shared__ float red[4];
    const int tid = threadIdx.x;
    const int i0 = tid >> 5, j = tid & 31;
    const int t_conv = *tconv_ptr;
    const float TOL = 1e-3f;

    for (int idx = tid; idx < NN; idx += 256) {
        float v = Sf_all[(size_t)(T - 1) * NN + idx];
        Ss[idx >> 5][idx & 31] = v;
        Ss_all[(size_t)(T - 1) * NN + idx] = v;
    }
    bar_lds();
    float prevSs[4];
    #pragma unroll
    for (int e = 0; e < 4; ++e) prevSs[e] = Ss[j][i0 + 8*e];

    for (int t = T - 2; t >= 0; --t) {
        float jr[4][32];
        #pragma unroll
        for (int e = 0; e < 4; ++e)
            load_row32(J_all + (size_t)t * NN + (i0 + 8*e) * 32, jr[e]);
        #pragma unroll
        for (int e = 0; e < 4; ++e)
            Hl[i0 + 8*e][j] = H_all[(size_t)t * NN + tid + 256*e];
        {
            float sc[32];
            #pragma unroll
            for (int k = 0; k < 32; ++k) sc[k] = Ss[k][j];
            #pragma unroll
            for (int e = 0; e < 4; ++e) {
                float s = 0.f;
                #pragma unroll
                for (int k = 0; k < 32; ++k) s += jr[e][k] * sc[k];
                W[i0 + 8*e][j] = s;
            }
        }
        bar_lds();
        float localmax = 0.f;
        {
            float wr[32];
            #pragma unroll
            for (int k = 0; k < 32; ++k) wr[k] = W[j][k];
            #pragma unroll
            for (int e = 0; e < 4; ++e) {
                const int c = i0 + 8*e;
                float s = Hl[j][c];
                #pragma unroll
                for (int k = 0; k < 32; ++k) s += wr[k] * jr[e][k];
                Ss[j][c] = s;
                Ss_all[(size_t)t * NN + tid + 256*e] = s;
                localmax = fmaxf(localmax, fabsf(s - prevSs[e]));
                prevSs[e] = s;
            }
        }
        #pragma unroll
        for (int m = 1; m < 64; m <<= 1)
            localmax = fmaxf(localmax, __shfl_xor(localmax, m));
        if ((tid & 63) == 0) red[tid >> 6] = localmax;
        bar_lds();
        const float g = fmaxf(fmaxf(red[0], red[1]), fmaxf(red[2], red[3]));
        if (g <= TOL && (t - 1 >= t_conv)) {
            for (int s = t_conv; s <= t - 1; ++s) {
                #pragma unroll
                for (int e = 0; e < 4; ++e)
                    Ss_all[(size_t)s * NN + tid + 256*e] = prevSs[e];
            }
            t = t_conv;
        }
    }
}

// ---------------- K4: per-batch means (R13 verbatim; plateau-constant G/J) -----
__global__ __launch_bounds__(64, 1) void k_mu(
    const float* __restrict__ Y, const float* __restrict__ U,
    const float* __restrict__ mu0,
    const float* __restrict__ K_all, const float* __restrict__ J_all,
    const float* __restrict__ G_all, const float* __restrict__ D_all,
    const float* __restrict__ E_all, const float* __restrict__ F_all,
    const int* __restrict__ tconv_ptr,
    float* __restrict__ out_mus)
{
    const int b = blockIdx.x;
    const int lane = threadIdx.x;
    const int j = lane & 31;
    const int half = lane >> 5;
    __shared__ float mfh[T][N];
    __shared__ float cfh[T][N];
    const int t_conv = *tconv_ptr;
    const float* Yb = Y + (size_t)b * T * P;
    const float* Ub = U + (size_t)b * T * M;

    // ---- forward pre-pass: c[t][j] = D_t[j,:]u_t + K_t[j,:]y_t ----
    for (int it = 0; it < T / 2; ++it) {
        const int t = it * 2 + half;
        float dr[16], kr[16], uu[16], yy[16];
        load_row16(D_all + t * NM + j * 16, dr);
        load_row16(K_all + t * NP + j * 16, kr);
        load_row16(Ub + t * M, uu);
        load_row16(Yb + t * P, yy);
        float s0 = 0.f, s1 = 0.f, s2 = 0.f, s3 = 0.f;
        #pragma unroll
        for (int m = 0; m < 16; m += 4) {
            s0 += dr[m+0]*uu[m+0]; s1 += dr[m+1]*uu[m+1];
            s2 += dr[m+2]*uu[m+2]; s3 += dr[m+3]*uu[m+3];
            s0 += kr[m+0]*yy[m+0]; s1 += kr[m+1]*yy[m+1];
            s2 += kr[m+2]*yy[m+2]; s3 += kr[m+3]*yy[m+3];
        }
        cfh[t][j] = (s0 + s1) + (s2 + s3);
    }
    __syncthreads();

    // ---- forward chain: mu = G_t mu + c_t ----
    float mu = mu0[j];
    float gr[32];
    load_row32(G_all + j * 32, gr);
    const int tv = (t_conv < T - 1) ? t_conv : (T - 1);
    float cn = cfh[0][j];
    int t = 0;
    for (; t < tv; ++t) {           // varying phase: per-step prefetch
        float grn[32];
        load_row32(G_all + (size_t)(t + 1) * NN + j * 32, grn);
        const float cnn = cfh[t + 1][j];
        float s0 = 0.f, s1 = 0.f, s2 = 0.f, s3 = 0.f;
        #pragma unroll
        for (int k = 0; k < 32; k += 4) {
            s0 += gr[k+0] * __shfl(mu, k+0);
            s1 += gr[k+1] * __shfl(mu, k+1);
            s2 += gr[k+2] * __shfl(mu, k+2);
            s3 += gr[k+3] * __shfl(mu, k+3);
        }
        mu = ((s0 + s1) + (s2 + s3)) + cn;
        if (lane < 32) mfh[t][j] = mu;
        #pragma unroll
        for (int c = 0; c < 32; ++c) gr[c] = grn[c];
        cn = cnn;
    }
    for (; t < T; ++t) {            // plateau: gr constant, zero loads
        const float cnn = (t + 1 < T) ? cfh[t + 1][j] : 0.f;
        float s0 = 0.f, s1 = 0.f, s2 = 0.f, s3 = 0.f;
        #pragma unroll
        for (int k = 0; k < 32; k += 4) {
            s0 += gr[k+0] * __shfl(mu, k+0);
            s1 += gr[k+1] * __shfl(mu, k+1);
            s2 += gr[k+2] * __shfl(mu, k+2);
            s3 += gr[k+3] * __shfl(mu, k+3);
        }
        mu = ((s0 + s1) + (s2 + s3)) + cn;
        if (lane < 32) mfh[t][j] = mu;
        cn = cnn;
    }
    if (lane < 32) out_mus[((size_t)b * T + (T - 1)) * N + j] = mu;
    __syncthreads();

    // ---- backward pre-pass: cb[t][j] = E_t[j,:]mfh[t] - F_t[j,:]u(t+1) ----
    for (int it = 0; it < T / 2; ++it) {
        const int tt = it * 2 + half;
        if (tt < T - 1) {
            float er[32], fr[16], uu[16];
            load_row32(E_all + (size_t)tt * NN + j * 32, er);
            load_row16(F_all + tt * NM + j * 16, fr);
            load_row16(Ub + (tt + 1) * M, uu);
            float s0 = 0.f, s1 = 0.f, s2 = 0.f, s3 = 0.f;
            #pragma unroll
            for (int k = 0; k < 32; k += 4) {
                s0 += er[k+0] * mfh[tt][k+0];
                s1 += er[k+1] * mfh[tt][k+1];
                s2 += er[k+2] * mfh[tt][k+2];
                s3 += er[k+3] * mfh[tt][k+3];
            }
            #pragma unroll
            for (int m = 0; m < 16; m += 4) {
                s0 -= fr[m+0]*uu[m+0]; s1 -= fr[m+1]*uu[m+1];
                s2 -= fr[m+2]*uu[m+2]; s3 -= fr[m+3]*uu[m+3];
            }
            cfh[tt][j] = (s0 + s1) + (s2 + s3);
        }
    }
    __syncthreads();

    // ---- backward chain: ms = J_t ms + cb_t ----
    float ms = mu;
    const int tp = (t_conv < T - 2) ? t_conv : (T - 2);
    float jr[32];
    load_row32(J_all + (size_t)tp * NN + j * 32, jr);   // J constant on [tp, T-2]
    float cb = cfh[T - 2][j];
    for (t = T - 2; t >= tp; --t) {   // plateau: jr constant, zero loads
        const float cbn = (t - 1 >= 0) ? cfh[t - 1][j] : 0.f;
        float s0 = 0.f, s1 = 0.f, s2 = 0.f, s3 = 0.f;
        #pragma unroll
        for (int k = 0; k < 32; k += 4) {
            s0 += jr[k+0] * __shfl(ms, k+0);
            s1 += jr[k+1] * __shfl(ms, k+1);
            s2 += jr[k+2] * __shfl(ms, k+2);
            s3 += jr[k+3] * __shfl(ms, k+3);
        }
        ms = ((s0 + s1) + (s2 + s3)) + cb;
        if (lane < 32) out_mus[((size_t)b * T + t) * N + j] = ms;
        cb = cbn;
    }
    if (t >= 0) {
        load_row32(J_all + (size_t)t * NN + j * 32, jr);   // J_{tp-1}
        for (; t >= 0; --t) {          // varying phase: per-step prefetch
            float jrn[32];
            #pragma unroll
            for (int c = 0; c < 32; ++c) jrn[c] = 0.f;
            if (t > 0) load_row32(J_all + (size_t)(t - 1) * NN + j * 32, jrn);
            const float cbn = (t - 1 >= 0) ? cfh[t - 1][j] : 0.f;
            float s0 = 0.f, s1 = 0.f, s2 = 0.f, s3 = 0.f;
            #pragma unroll
            for (int k = 0; k < 32; k += 4) {
                s0 += jr[k+0] * __shfl(ms, k+0);
                s1 += jr[k+1] * __shfl(ms, k+1);
                s2 += jr[k+2] * __shfl(ms, k+2);
                s3 += jr[k+3] * __shfl(ms, k+3);
            }
            ms = ((s0 + s1) + (s2 + s3)) + cb;
            if (lane < 32) out_mus[((size_t)b * T + t) * N + j] = ms;
            cb = cbn;
            #pragma unroll
            for (int c = 0; c < 32; ++c) jr[c] = jrn[c];
        }
    }
}

// ---------------- K5: broadcast Sig_s tiles (nt stream write, verbatim) --------
__global__ __launch_bounds__(256) void k_bcast(
    const float* __restrict__ Ss_all, f4* __restrict__ out4)
{
    const f4* src = (const f4*)Ss_all;
    const long long total = (long long)BB * T * (NN / 4);
    const long long stride = (long long)gridDim.x * blockDim.x;
    for (long long g = blockIdx.x * (long long)blockDim.x + threadIdx.x; g < total; g += stride) {
        int e4 = (int)(g & 255);
        long long bt = g >> 8;
        int t = (int)(bt & (T - 1));
        __builtin_nontemporal_store(src[t * 256 + e4], &out4[g]);
    }
}

extern "C" void kernel_launch(void* const* d_in, const int* in_sizes, int n_in,
                              void* d_out, int out_size, void* d_ws, size_t ws_size,
                              hipStream_t stream)
{
    (void)in_sizes; (void)n_in; (void)out_size; (void)ws_size;
    const float* Y      = (const float*)d_in[0];
    const float* U      = (const float*)d_in[1];
    const float* A      = (const float*)d_in[2];
    const float* Bm     = (const float*)d_in[3];
    const float* C      = (const float*)d_in[4];
    const float* mu0    = (const float*)d_in[5];
    const float* Sigma0 = (const float*)d_in[6];
    const float* Q      = (const float*)d_in[7];
    const float* R      = (const float*)d_in[8];

    float* ws     = (float*)d_ws;
    float* K_all  = ws;
    float* Sp_all = K_all + T * NP;
    float* Sf_all = Sp_all + T * NN;
    float* J_all  = Sf_all + T * NN;
    float* H_all  = J_all + T * NN;
    float* Ss_all = H_all + T * NN;
    float* G_all  = Ss_all + T * NN;
    float* D_all  = G_all + T * NN;
    float* E_all  = D_all + T * NM;
    float* F_all  = E_all + T * NN;
    int*   tconv  = (int*)(F_all + T * NM);

    float* out_mus  = (float*)d_out;
    float* out_sigs = out_mus + (size_t)BB * T * N;

    hipLaunchKernelGGL(k_fwd,   dim3(1),    dim3(256), 0, stream, A, C, Q, R, Sigma0, K_all, Sp_all, Sf_all, tconv);
    hipLaunchKernelGGL(k_jhm,   dim3(T),    dim3(256), 0, stream, A, C, Bm, Sp_all, Sf_all, K_all, J_all, H_all, G_all, D_all, E_all, F_all);
    hipLaunchKernelGGL(k_sscan, dim3(1),    dim3(256), 0, stream, Sf_all, J_all, H_all, Ss_all, tconv);
    hipLaunchKernelGGL(k_mu,    dim3(BB),   dim3(64),  0, stream, Y, U, mu0, K_all, J_all, G_all, D_all, E_all, F_all, tconv, out_mus);
    hipLaunchKernelGGL(k_bcast, dim3(4096), dim3(256), 0, stream, Ss_all, (f4*)out_sigs);
}